// Round 1
// baseline (596.317 us; speedup 1.0000x reference)
//
#include <hip/hip_runtime.h>
#include <hip/hip_bf16.h>

// InvertedResidual (ShuffleNet-v2 right branch) fused pipeline.
// out[:, 2c]   = x[:, c]          (c < 116)   -- shuffle of passthrough half
// out[:, 2c+1] = branch(x[:, 116+c])          -- conv1x1/bn/prelu -> dw3x3/bn -> conv1x1/bn/prelu
//
// h1 intermediate lives in d_ws as bf16, pixel-major [b][p][128] (channels padded
// 116->128 with zeros) so dwconv vectorizes over channels and conv2 A-frags
// (8 contiguous k per lane) read directly.

#define BATCH 64
#define CTOT  232
#define BFC   116
#define HW    3136
#define WD    56
#define CP    128
#define EPSV  1e-5f

typedef unsigned short u16;
typedef __attribute__((ext_vector_type(8))) short short8;
typedef __attribute__((ext_vector_type(4))) float float4v;

__device__ __forceinline__ u16 f2bf(float f) {
    union { float f; unsigned u; } v; v.f = f;
    unsigned r = v.u + 0x7FFF + ((v.u >> 16) & 1);
    return (u16)(r >> 16);
}
__device__ __forceinline__ float bf2f(u16 u) {
    union { unsigned u; float f; } v; v.u = ((unsigned)u) << 16;
    return v.f;
}

// ---------------- Kernel A: passthrough half with shuffle (even channels) ----
__global__ __launch_bounds__(256) void shuffle_copy(const float* __restrict__ x,
                                                    float* __restrict__ out) {
    int bc = blockIdx.x;              // 0 .. 64*116-1
    int b = bc / BFC, c = bc % BFC;
    const float4v* src = (const float4v*)(x + ((size_t)b * CTOT + c) * HW);
    float4v* dst = (float4v*)(out + ((size_t)b * CTOT + 2 * c) * HW);
    for (int i = threadIdx.x; i < HW / 4; i += 256) dst[i] = src[i];
}

// ---------------- Kernel B: conv1x1 #1 + bn1 + prelu -> h1 (bf16, [b][p][128])
__global__ __launch_bounds__(256) void conv1_kernel(
    const float* __restrict__ x, const float* __restrict__ w2,
    const float* __restrict__ g1, const float* __restrict__ b1,
    const float* __restrict__ m1, const float* __restrict__ v1,
    const float* __restrict__ al1, u16* __restrict__ h1) {
    __shared__ __align__(16) u16 aF[8 * 4 * 64 * 8];   // 32 KB: x A-frags (pixels x K)
    __shared__ __align__(16) u16 bF[8 * 4 * 64 * 8];   // 32 KB: W2 B-frags (K x outch)
    int tid = threadIdx.x;
    int p0 = blockIdx.x * 128;        // pixel tile base (25 tiles, last partial)
    int b = blockIdx.y;
    const float* x2 = x + ((size_t)b * CTOT + BFC) * HW;

    // stage x tile into A-frag layout: A[m=pixel][k=chan], lane=(kq<<4)|pix15, j=k&7
    {
        int c_off = tid >> 7;         // 0..1
        int pp = tid & 127;
        int p = p0 + pp;
        bool pv = p < HW;
        int mt = pp >> 4, lsub = pp & 15;
        for (int cb = 0; cb < CP; cb += 2) {
            int c = cb + c_off;
            float val = (pv && c < BFC) ? x2[(size_t)c * HW + p] : 0.f;
            int kt = c >> 5;
            int lane = (((c >> 3) & 3) << 4) | lsub;
            aF[(((mt << 2) + kt) * 64 + lane) * 8 + (c & 7)] = f2bf(val);
        }
    }
    // stage W2 into B-frag layout: B[k=chan][n=outch]
    {
        int lane = tid & 63, w = tid >> 6;
        for (int fid = w; fid < 32; fid += 4) {
            int nt = fid >> 2, kt = fid & 3;
            int o = nt * 16 + (lane & 15);
            int cb = kt * 32 + ((lane >> 4) << 3);
            short8 vv;
            for (int j = 0; j < 8; j++) {
                int c = cb + j;
                float val = (o < BFC && c < BFC) ? w2[o * BFC + c] : 0.f;
                ((u16*)&vv)[j] = f2bf(val);
            }
            *(short8*)&bF[(fid * 64 + lane) * 8] = vv;
        }
    }
    __syncthreads();

    int lane = tid & 63, w = tid >> 6;
    short8 a0[4], a1[4];
    for (int kt = 0; kt < 4; kt++) {
        a0[kt] = *(const short8*)&aF[(((2 * w) * 4 + kt) * 64 + lane) * 8];
        a1[kt] = *(const short8*)&aF[(((2 * w + 1) * 4 + kt) * 64 + lane) * 8];
    }
    float a1s = al1[0];
    u16* h1p = h1 + (size_t)b * HW * CP;
    for (int nt = 0; nt < 8; nt++) {
        float4v acc0 = {0.f, 0.f, 0.f, 0.f}, acc1 = {0.f, 0.f, 0.f, 0.f};
        for (int kt = 0; kt < 4; kt++) {
            short8 bb = *(const short8*)&bF[((nt * 4 + kt) * 64 + lane) * 8];
            acc0 = __builtin_amdgcn_mfma_f32_16x16x32_bf16(a0[kt], bb, acc0, 0, 0, 0);
            acc1 = __builtin_amdgcn_mfma_f32_16x16x32_bf16(a1[kt], bb, acc1, 0, 0, 0);
        }
        int o = nt * 16 + (lane & 15);
        float sc = 0.f, sh = 0.f;
        if (o < BFC) {
            sc = g1[o] * rsqrtf(v1[o] + EPSV);
            sh = b1[o] - m1[o] * sc;
        }
        for (int half = 0; half < 2; half++) {
            float4v acc = half ? acc1 : acc0;
            int mt = 2 * w + half;
            int prow = p0 + mt * 16 + ((lane >> 4) << 2);
            for (int r = 0; r < 4; r++) {
                int p = prow + r;
                if (p < HW) {
                    float y = 0.f;
                    if (o < BFC) {
                        y = acc[r] * sc + sh;
                        y = y >= 0.f ? y : a1s * y;
                    }
                    h1p[(size_t)p * CP + o] = f2bf(y);  // pad chans get 0
                }
            }
        }
    }
}

// ---------------- Kernel C: dwconv3x3+bn2 -> conv1x1 #2 + bn3 + prelu --------
__global__ __launch_bounds__(256) void conv2_kernel(
    const u16* __restrict__ h1, const float* __restrict__ wdw,
    const float* __restrict__ g2, const float* __restrict__ b2,
    const float* __restrict__ m2, const float* __restrict__ v2,
    const float* __restrict__ w3,
    const float* __restrict__ g3, const float* __restrict__ b3,
    const float* __restrict__ m3, const float* __restrict__ v3,
    const float* __restrict__ al2, float* __restrict__ out) {
    __shared__ __align__(16) u16 h2F[7 * 4 * 64 * 8];   // 28 KB: h2 A-frags (112 px)
    __shared__ __align__(16) u16 reg1[8 * 4 * 64 * 8];  // 32 KB: union {wdw+bn2} then {W3 frags}
    int tid = threadIdx.x;
    int b = blockIdx.y;
    int r0 = blockIdx.x * 2;          // 2 output rows per block, 28 blocks
    int p0 = r0 * WD;
    float* f1 = (float*)reg1;

    // stage dw weights transposed [tap][c] + bn2 scale/shift
    for (int idx = tid; idx < 1152 + 256; idx += 256) {
        if (idx < 1152) {
            int tap = idx >> 7, c = idx & 127;
            f1[idx] = (c < BFC) ? wdw[c * 9 + tap] : 0.f;
        } else if (idx < 1280) {
            int c = idx - 1152;
            f1[1152 + c] = (c < BFC) ? g2[c] * rsqrtf(v2[c] + EPSV) : 0.f;
        } else {
            int c = idx - 1280;
            float sh = 0.f;
            if (c < BFC) { float sc = g2[c] * rsqrtf(v2[c] + EPSV); sh = b2[c] - m2[c] * sc; }
            f1[1280 + c] = sh;
        }
    }
    __syncthreads();

    // phase 1: dwconv over 112 px x 16 channel-octets -> h2 A-frag layout in LDS
    const u16* h1b = h1 + (size_t)b * HW * CP;
    for (int it = 0; it < 7; it++) {
        int t = it * 256 + tid;       // 0..1791
        int g = t & 15, pl = t >> 4;  // octet, local pixel (0..111)
        int rr = (pl >= WD) ? 1 : 0;
        int col = pl - rr * WD;
        int row = r0 + rr;
        float acc[8];
        for (int j = 0; j < 8; j++) acc[j] = 0.f;
        for (int dy = -1; dy <= 1; dy++) {
            int y = row + dy;
            if (y < 0 || y >= WD) continue;
            for (int dx = -1; dx <= 1; dx++) {
                int xc = col + dx;
                if (xc < 0 || xc >= WD) continue;
                int tap = (dy + 1) * 3 + (dx + 1);
                short8 hv = *(const short8*)(h1b + ((size_t)(y * WD + xc)) * CP + g * 8);
                const u16* us = (const u16*)&hv;
                const float* wv = &f1[tap * 128 + g * 8];
                for (int j = 0; j < 8; j++) acc[j] += bf2f(us[j]) * wv[j];
            }
        }
        short8 hv;
        for (int j = 0; j < 8; j++) {
            int c = g * 8 + j;
            ((u16*)&hv)[j] = f2bf(acc[j] * f1[1152 + c] + f1[1280 + c]);
        }
        int mt = pl >> 4, kt = g >> 2;
        int lane = ((g & 3) << 4) | (pl & 15);
        *(short8*)&h2F[((mt * 4 + kt) * 64 + lane) * 8] = hv;
    }
    __syncthreads();

    // restage reg1 as W3 B-frags
    int lane = tid & 63, w = tid >> 6;
    for (int fid = w; fid < 32; fid += 4) {
        int nt = fid >> 2, kt = fid & 3;
        int o = nt * 16 + (lane & 15);
        int cb = kt * 32 + ((lane >> 4) << 3);
        short8 vv;
        for (int j = 0; j < 8; j++) {
            int c = cb + j;
            float val = (o < BFC && c < BFC) ? w3[o * BFC + c] : 0.f;
            ((u16*)&vv)[j] = f2bf(val);
        }
        *(short8*)&reg1[(fid * 64 + lane) * 8] = vv;
    }
    __syncthreads();

    // phase 2: GEMM  M=112 px (7 mt) x N=128 outch, each wave owns 2 nt
    float a2s = al2[0];
    short8 bf0[2][4];
    for (int i = 0; i < 2; i++)
        for (int kt = 0; kt < 4; kt++)
            bf0[i][kt] = *(const short8*)&reg1[(((2 * w + i) * 4 + kt) * 64 + lane) * 8];
    for (int mt = 0; mt < 7; mt++) {
        short8 af[4];
        for (int kt = 0; kt < 4; kt++)
            af[kt] = *(const short8*)&h2F[((mt * 4 + kt) * 64 + lane) * 8];
        for (int i = 0; i < 2; i++) {
            float4v acc = {0.f, 0.f, 0.f, 0.f};
            for (int kt = 0; kt < 4; kt++)
                acc = __builtin_amdgcn_mfma_f32_16x16x32_bf16(af[kt], bf0[i][kt], acc, 0, 0, 0);
            int nt = 2 * w + i;
            int o = nt * 16 + (lane & 15);
            if (o < BFC) {
                float sc = g3[o] * rsqrtf(v3[o] + EPSV);
                float sh = b3[o] - m3[o] * sc;
                int plb = mt * 16 + ((lane >> 4) << 2);
                float4v ov;
                for (int r = 0; r < 4; r++) {
                    float y = acc[r] * sc + sh;
                    ov[r] = y >= 0.f ? y : a2s * y;
                }
                *(float4v*)&out[((size_t)b * CTOT + 2 * o + 1) * HW + p0 + plb] = ov;
            }
        }
    }
}

extern "C" void kernel_launch(void* const* d_in, const int* in_sizes, int n_in,
                              void* d_out, int out_size, void* d_ws, size_t ws_size,
                              hipStream_t stream) {
    const float* x   = (const float*)d_in[0];
    const float* w2  = (const float*)d_in[1];
    const float* g1  = (const float*)d_in[2];
    const float* b1  = (const float*)d_in[3];
    const float* m1  = (const float*)d_in[4];
    const float* v1  = (const float*)d_in[5];
    const float* al1 = (const float*)d_in[6];
    const float* wdw = (const float*)d_in[7];
    const float* g2  = (const float*)d_in[8];
    const float* b2  = (const float*)d_in[9];
    const float* m2  = (const float*)d_in[10];
    const float* v2  = (const float*)d_in[11];
    const float* w3  = (const float*)d_in[12];
    const float* g3  = (const float*)d_in[13];
    const float* b3  = (const float*)d_in[14];
    const float* m3  = (const float*)d_in[15];
    const float* v3  = (const float*)d_in[16];
    const float* al2 = (const float*)d_in[17];
    float* out = (float*)d_out;
    u16* h1 = (u16*)d_ws;   // 64*3136*128*2 = 51.4 MB

    hipLaunchKernelGGL(shuffle_copy, dim3(BATCH * BFC), dim3(256), 0, stream, x, out);
    hipLaunchKernelGGL(conv1_kernel, dim3(25, BATCH), dim3(256), 0, stream,
                       x, w2, g1, b1, m1, v1, al1, h1);
    hipLaunchKernelGGL(conv2_kernel, dim3(28, BATCH), dim3(256), 0, stream,
                       h1, wdw, g2, b2, m2, v2, w3, g3, b3, m3, v3, al2, out);
}

// Round 2
// 530.710 us; speedup vs baseline: 1.1236x; 1.1236x over previous
//
#include <hip/hip_runtime.h>
#include <hip/hip_bf16.h>

// Fused InvertedResidual:
//   prep: fold BN1 into W2 (+bias1), BN2+BN3 into W3 (+bias3), transpose dw weights.
//   k1:   conv1x1(GEMM, bf16 MFMA) + prelu -> h1 in LDS (per 2-row strip, halo
//         recomputed) -> raw dwconv3x3 -> h2 (bf16 [b][p][120]) in d_ws.
//   k2:   conv1x1 #2 (GEMM, A-frags straight from h2 global) + bias3 + prelu ->
//         odd output channels; even channels = strided copy of x (folded in).

#define BATCH 64
#define CTOT  232
#define BFC   116
#define HW    3136
#define WD    56
#define CH2   120          // h1s/h2 channel stride (15 octets)
#define EPSV  1e-5f

typedef unsigned short u16;
typedef __attribute__((ext_vector_type(8))) short short8;
typedef __attribute__((ext_vector_type(4))) float float4v;

// d_ws layout (bytes)
#define WS_W2P   0          // u16[128*128]
#define WS_W3P   32768      // u16[128*128]
#define WS_WDWT  65536      // float[9*120]
#define WS_B1P   69888      // float[128]
#define WS_B3P   70400      // float[128]
#define WS_H2    131072     // u16[64*3136*120] = 48,168,960 B (total 48.3 MB < 51.38 MB known-safe)

__device__ __forceinline__ u16 f2bf(float f) {
    union { float f; unsigned u; } v; v.f = f;
    unsigned r = v.u + 0x7FFF + ((v.u >> 16) & 1);
    return (u16)(r >> 16);
}
__device__ __forceinline__ float bf2f(u16 u) {
    union { unsigned u; float f; } v; v.u = ((unsigned)u) << 16;
    return v.f;
}

// ---------------- prep: weight folding ----------------
__global__ __launch_bounds__(256) void prep(
    const float* __restrict__ w2, const float* __restrict__ g1, const float* __restrict__ b1,
    const float* __restrict__ m1, const float* __restrict__ v1,
    const float* __restrict__ wdw,
    const float* __restrict__ g2, const float* __restrict__ b2,
    const float* __restrict__ m2, const float* __restrict__ v2,
    const float* __restrict__ w3, const float* __restrict__ g3, const float* __restrict__ b3,
    const float* __restrict__ m3, const float* __restrict__ v3,
    char* __restrict__ ws) {
    u16* w2p = (u16*)(ws + WS_W2P);
    u16* w3p = (u16*)(ws + WS_W3P);
    float* wdwt = (float*)(ws + WS_WDWT);
    float* b1p = (float*)(ws + WS_B1P);
    float* b3p = (float*)(ws + WS_B3P);
    int tid = threadIdx.x;
    int bx = blockIdx.x;
    if (bx < 8) {                                  // w2p = sc1[o] * w2[o][c], padded 128x128
        int o = bx * 16 + (tid >> 4);
        int cs = (tid & 15) * 8;
        float sc = (o < BFC) ? g1[o] * rsqrtf(v1[o] + EPSV) : 0.f;
        short8 v;
        for (int j = 0; j < 8; j++) {
            int c = cs + j;
            float val = (o < BFC && c < BFC) ? sc * w2[o * BFC + c] : 0.f;
            ((u16*)&v)[j] = f2bf(val);
        }
        *(short8*)&w2p[o * 128 + cs] = v;
    } else if (bx < 16) {                          // w3p = sc3[o]*sc2[c]*w3[o][c]
        int o = (bx - 8) * 16 + (tid >> 4);
        int cs = (tid & 15) * 8;
        float sc = (o < BFC) ? g3[o] * rsqrtf(v3[o] + EPSV) : 0.f;
        short8 v;
        for (int j = 0; j < 8; j++) {
            int c = cs + j;
            float val = 0.f;
            if (o < BFC && c < BFC) {
                float sc2 = g2[c] * rsqrtf(v2[c] + EPSV);
                val = sc * sc2 * w3[o * BFC + c];
            }
            ((u16*)&v)[j] = f2bf(val);
        }
        *(short8*)&w3p[o * 128 + cs] = v;
    } else {
        if (tid < CH2)                             // dw weights transposed [tap][c]
            for (int tap = 0; tap < 9; tap++)
                wdwt[tap * CH2 + tid] = (tid < BFC) ? wdw[tid * 9 + tap] : 0.f;
        if (tid < 128) {
            float b1v = 0.f, b3v = 0.f;
            if (tid < BFC) {
                float sc1 = g1[tid] * rsqrtf(v1[tid] + EPSV);
                b1v = b1[tid] - m1[tid] * sc1;
                float sc3 = g3[tid] * rsqrtf(v3[tid] + EPSV);
                float s = 0.f;
                for (int c = 0; c < BFC; c++) {     // fold bn2 shift through w3
                    float sc2 = g2[c] * rsqrtf(v2[c] + EPSV);
                    float sh2 = b2[c] - m2[c] * sc2;
                    s += w3[tid * BFC + c] * sh2;
                }
                b3v = (b3[tid] - m3[tid] * sc3) + sc3 * s;
            }
            b1p[tid] = b1v;
            b3p[tid] = b3v;
        }
    }
}

// ---------------- k1: conv1 (GEMM) + prelu -> LDS h1 -> dwconv3x3 -> h2 ------
__global__ __launch_bounds__(256, 3) void k1(const float* __restrict__ x,
        const float* __restrict__ al1, char* __restrict__ ws) {
    __shared__ u16 h1s[224 * CH2];                 // 53,760 B -> 3 blocks/CU
    const u16* w2p = (const u16*)(ws + WS_W2P);
    const float* wdwt = (const float*)(ws + WS_WDWT);
    const float* b1p = (const float*)(ws + WS_B1P);
    u16* h2g = (u16*)(ws + WS_H2);

    int tid = threadIdx.x;
    int lane = tid & 63;
    int w = tid >> 6;
    int l15 = lane & 15, kq = lane >> 4;
    int b = blockIdx.y;
    int r0 = blockIdx.x * 2;                       // 2 output rows per block
    int p_in0 = r0 * WD - WD;                      // strip rows r0-1 .. r0+2 (224 px)

    const float* x2 = x + ((size_t)b * CTOT + BFC) * HW;
    float a1 = al1[0];

    // ---- Phase A: GEMM1, waves split 2x2 (M-half x N-half) ----
    int mh = w >> 1, nh = w & 1;
    short8 bfr[4][4];
    float biasv[4];
    for (int ni = 0; ni < 4; ni++) {
        int o = (nh * 4 + ni) * 16 + l15;
        for (int kt = 0; kt < 4; kt++)
            bfr[ni][kt] = *(const short8*)&w2p[o * 128 + kt * 32 + kq * 8];
        biasv[ni] = b1p[o];
    }
    for (int mi = 0; mi < 7; mi++) {
        int mt = mh * 7 + mi;
        int p = p_in0 + mt * 16 + l15;
        bool pv = (p >= 0) && (p < HW);
        short8 afr[4];
        for (int kt = 0; kt < 4; kt++) {           // A-frag straight from global
            short8 av;
            for (int j = 0; j < 8; j++) {
                int c = kt * 32 + kq * 8 + j;
                float v = 0.f;
                if (pv && c < BFC) v = x2[(size_t)c * HW + p];
                ((u16*)&av)[j] = f2bf(v);
            }
            afr[kt] = av;
        }
        for (int ni = 0; ni < 4; ni++) {
            float4v acc = {0.f, 0.f, 0.f, 0.f};
            for (int kt = 0; kt < 4; kt++)
                acc = __builtin_amdgcn_mfma_f32_16x16x32_bf16(afr[kt], bfr[ni][kt], acc, 0, 0, 0);
            int o = (nh * 4 + ni) * 16 + l15;
            if (o < CH2) {
                int plb = mt * 16 + kq * 4;
                for (int r = 0; r < 4; r++) {
                    int pl = plb + r;
                    int pim = p_in0 + pl;
                    float y = acc[r] + biasv[ni];
                    y = y >= 0.f ? y : a1 * y;
                    // out-of-image rows must be ZERO in h1 (dwconv zero-padding)
                    h1s[pl * CH2 + o] = (pim >= 0 && pim < HW) ? f2bf(y) : (u16)0;
                }
            }
        }
    }
    __syncthreads();

    // ---- Phase B: raw dwconv3x3 (bn2 folded into w3p/bias3) ----
    for (int u = tid; u < 420; u += 256) {         // 28 px-quads x 15 octets
        int oct = u % 15;
        int pq = u / 15;
        int rr = pq / 14;
        int col0 = (pq % 14) * 4;
        float acc[4][8];
        for (int i = 0; i < 4; i++)
            for (int j = 0; j < 8; j++) acc[i][j] = 0.f;
        for (int dy = 0; dy < 3; dy++) {
            int lr = rr + dy;                      // h1s rows rr..rr+2
            float f[6][8];
            for (int k = 0; k < 6; k++) {
                int ci = col0 - 1 + k;
                if (ci >= 0 && ci < WD) {
                    short8 v = *(const short8*)&h1s[(lr * WD + ci) * CH2 + oct * 8];
                    for (int j = 0; j < 8; j++) f[k][j] = bf2f(((const u16*)&v)[j]);
                } else {
                    for (int j = 0; j < 8; j++) f[k][j] = 0.f;
                }
            }
            for (int dx = 0; dx < 3; dx++) {
                const float* wt = &wdwt[(dy * 3 + dx) * CH2 + oct * 8];
                float4v w0 = *(const float4v*)&wt[0];
                float4v w1 = *(const float4v*)&wt[4];
                float w8[8] = {w0[0], w0[1], w0[2], w0[3], w1[0], w1[1], w1[2], w1[3]};
                for (int i = 0; i < 4; i++)
                    for (int j = 0; j < 8; j++)
                        acc[i][j] += f[i + dx][j] * w8[j];
            }
        }
        int prow = (r0 + rr) * WD + col0;
        u16* dst = h2g + ((size_t)b * HW + prow) * CH2 + oct * 8;
        for (int i = 0; i < 4; i++) {
            short8 ov;
            for (int j = 0; j < 8; j++) ((u16*)&ov)[j] = f2bf(acc[i][j]);
            *(short8*)&dst[(size_t)i * CH2] = ov;
        }
    }
}

// ---------------- k2: conv1x1 #2 + bias3 + prelu -> odd channels; copy even --
__global__ __launch_bounds__(256) void k2(const float* __restrict__ x,
        const float* __restrict__ al2, const char* __restrict__ ws,
        float* __restrict__ out) {
    int tid = threadIdx.x;
    int b = blockIdx.y;
    int bx = blockIdx.x;
    if (bx >= 25) {                                // folded shuffle-copy blocks
        int c0 = (bx - 25) * 15;
        int c1 = c0 + 15 < BFC ? c0 + 15 : BFC;
        for (int c = c0; c < c1; c++) {
            const float4v* src = (const float4v*)(x + ((size_t)b * CTOT + c) * HW);
            float4v* dst = (float4v*)(out + ((size_t)b * CTOT + 2 * c) * HW);
            for (int i = tid; i < HW / 4; i += 256) dst[i] = src[i];
        }
        return;
    }
    const u16* w3p = (const u16*)(ws + WS_W3P);
    const float* b3p = (const float*)(ws + WS_B3P);
    const u16* h2g = (const u16*)(ws + WS_H2);
    int lane = tid & 63, w = tid >> 6;
    int l15 = lane & 15, kq = lane >> 4;
    int p0 = bx * 128;
    float a2 = al2[0];
    short8 bfr[2][4];
    float biasv[2];
    for (int i = 0; i < 2; i++) {
        int o = (2 * w + i) * 16 + l15;
        for (int kt = 0; kt < 4; kt++)
            bfr[i][kt] = *(const short8*)&w3p[o * 128 + kt * 32 + kq * 8];
        biasv[i] = b3p[o];
    }
    const u16* h2b = h2g + (size_t)b * HW * CH2;
    short8 z8 = {0, 0, 0, 0, 0, 0, 0, 0};
    for (int mt = 0; mt < 8; mt++) {
        int p = p0 + mt * 16 + l15;
        bool pv = p < HW;
        const u16* arow = h2b + (size_t)p * CH2;
        short8 afr[4];
        for (int kt = 0; kt < 4; kt++) {           // A-frag straight from h2
            short8 av = z8;
            if (pv && !(kt == 3 && kq == 3)) av = *(const short8*)&arow[kt * 32 + kq * 8];
            afr[kt] = av;
        }
        for (int i = 0; i < 2; i++) {
            float4v acc = {0.f, 0.f, 0.f, 0.f};
            for (int kt = 0; kt < 4; kt++)
                acc = __builtin_amdgcn_mfma_f32_16x16x32_bf16(afr[kt], bfr[i][kt], acc, 0, 0, 0);
            int o = (2 * w + i) * 16 + l15;
            int pq = p0 + mt * 16 + kq * 4;
            if (o < BFC && pq < HW) {
                float4v ov;
                for (int r = 0; r < 4; r++) {
                    float y = acc[r] + biasv[i];
                    ov[r] = y >= 0.f ? y : a2 * y;
                }
                *(float4v*)&out[((size_t)b * CTOT + 2 * o + 1) * HW + pq] = ov;
            }
        }
    }
}

extern "C" void kernel_launch(void* const* d_in, const int* in_sizes, int n_in,
                              void* d_out, int out_size, void* d_ws, size_t ws_size,
                              hipStream_t stream) {
    const float* x   = (const float*)d_in[0];
    const float* w2  = (const float*)d_in[1];
    const float* g1  = (const float*)d_in[2];
    const float* b1  = (const float*)d_in[3];
    const float* m1  = (const float*)d_in[4];
    const float* v1  = (const float*)d_in[5];
    const float* al1 = (const float*)d_in[6];
    const float* wdw = (const float*)d_in[7];
    const float* g2  = (const float*)d_in[8];
    const float* b2  = (const float*)d_in[9];
    const float* m2  = (const float*)d_in[10];
    const float* v2  = (const float*)d_in[11];
    const float* w3  = (const float*)d_in[12];
    const float* g3  = (const float*)d_in[13];
    const float* b3  = (const float*)d_in[14];
    const float* m3  = (const float*)d_in[15];
    const float* v3  = (const float*)d_in[16];
    const float* al2 = (const float*)d_in[17];
    float* out = (float*)d_out;
    char* ws = (char*)d_ws;

    hipLaunchKernelGGL(prep, dim3(17), dim3(256), 0, stream,
                       w2, g1, b1, m1, v1, wdw, g2, b2, m2, v2, w3, g3, b3, m3, v3, ws);
    hipLaunchKernelGGL(k1, dim3(28, BATCH), dim3(256), 0, stream, x, al1, ws);
    hipLaunchKernelGGL(k2, dim3(33, BATCH), dim3(256), 0, stream, x, al2, ws, out);
}